// Round 1
// baseline (769.707 us; speedup 1.0000x reference)
//
#include <hip/hip_runtime.h>
#include <math.h>

// Problem constants (DUQ head)
#define B_      1024
#define EMBED_  768
#define HIDDEN_ 2048
#define C_      200
#define E_      256
#define EPS_    1e-5f
// log_kernel = -dist_sq / (2*0.1^2) = -50*dist_sq
#define NEG_INV_2LS2 (-50.0f)

__device__ __forceinline__ float gelu_exact(float x) {
    return 0.5f * x * (1.0f + erff(x * 0.70710678118654752f));
}

// ---------------- LayerNorm: one block (256 thr) per row ----------------
template<int COLS>
__global__ __launch_bounds__(256)
void ln_kernel(const float* __restrict__ x, const float* __restrict__ g,
               const float* __restrict__ b, float* __restrict__ out) {
    const int row = blockIdx.x;
    const int tid = threadIdx.x;
    constexpr int NT  = 256;
    constexpr int PER = COLS / NT; // 3 (768) or 8 (2048)
    float v[PER];
    float s = 0.f, s2 = 0.f;
    const float* xr = x + (size_t)row * COLS;
    #pragma unroll
    for (int i = 0; i < PER; ++i) {
        v[i] = xr[tid + i * NT];
        s  += v[i];
        s2 += v[i] * v[i];
    }
    #pragma unroll
    for (int off = 32; off > 0; off >>= 1) {
        s  += __shfl_down(s,  off, 64);
        s2 += __shfl_down(s2, off, 64);
    }
    __shared__ float sbuf[4], s2buf[4], stat[2];
    const int wid = tid >> 6;
    if ((tid & 63) == 0) { sbuf[wid] = s; s2buf[wid] = s2; }
    __syncthreads();
    if (tid == 0) {
        float ts = 0.f, ts2 = 0.f;
        #pragma unroll
        for (int i = 0; i < NT / 64; ++i) { ts += sbuf[i]; ts2 += s2buf[i]; }
        float mu  = ts / COLS;
        float var = ts2 / COLS - mu * mu;
        stat[0] = mu;
        stat[1] = rsqrtf(var + EPS_);
    }
    __syncthreads();
    const float mu = stat[0], rstd = stat[1];
    float* orow = out + (size_t)row * COLS;
    #pragma unroll
    for (int i = 0; i < PER; ++i) {
        int c = tid + i * NT;
        orow[c] = (v[i] - mu) * rstd * g[c] + b[c];
    }
}

// ---------------- fp32 GEMM: C = act(A @ W + bias) ----------------
// A [M,K] row-major, W [K,N] row-major, C [M,N] row-major.
// 256 threads as 16x16; each thread computes TM x TN micro-tile.
template<int BM, int BN, int BK, int TM, int TN, int ACT>
__global__ __launch_bounds__(256)
void gemm_kernel(const float* __restrict__ A, const float* __restrict__ W,
                 const float* __restrict__ bias, float* __restrict__ Cmat,
                 int M, int N, int K) {
    __shared__ float As[BK][BM + 4];
    __shared__ float Bs[BK][BN + 4];
    const int tid = threadIdx.x;
    const int tx  = tid & 15;
    const int ty  = tid >> 4;
    const int row0 = blockIdx.y * BM;
    const int col0 = blockIdx.x * BN;

    float acc[TM][TN];
    #pragma unroll
    for (int i = 0; i < TM; ++i)
        #pragma unroll
        for (int j = 0; j < TN; ++j) acc[i][j] = 0.f;

    constexpr int A_ELEMS = BM * BK / 256;
    constexpr int B_ELEMS = BK * BN / 256;

    for (int k0 = 0; k0 < K; k0 += BK) {
        #pragma unroll
        for (int i = 0; i < A_ELEMS; ++i) {
            int idx = tid + i * 256;
            int m = idx / BK, k = idx % BK;
            As[k][m] = A[(size_t)(row0 + m) * K + k0 + k];
        }
        #pragma unroll
        for (int i = 0; i < B_ELEMS; ++i) {
            int idx = tid + i * 256;
            int k = idx / BN, n = idx % BN;
            Bs[k][n] = W[(size_t)(k0 + k) * N + col0 + n];
        }
        __syncthreads();
        #pragma unroll
        for (int kk = 0; kk < BK; ++kk) {
            float af[TM], bf[TN];
            #pragma unroll
            for (int i = 0; i < TM; ++i) af[i] = As[kk][ty * TM + i];
            #pragma unroll
            for (int j = 0; j < TN; ++j) bf[j] = Bs[kk][tx * TN + j];
            #pragma unroll
            for (int i = 0; i < TM; ++i)
                #pragma unroll
                for (int j = 0; j < TN; ++j)
                    acc[i][j] = fmaf(af[i], bf[j], acc[i][j]);
        }
        __syncthreads();
    }

    #pragma unroll
    for (int i = 0; i < TM; ++i) {
        int r = row0 + ty * TM + i;
        #pragma unroll
        for (int j = 0; j < TN; ++j) {
            int c = col0 + tx * TN + j;
            float v = acc[i][j] + bias[c];
            if (ACT == 1) v = gelu_exact(v);
            Cmat[(size_t)r * N + c] = v;
        }
    }
}

// ---------------- per-class RBF distance ----------------
// grid (B/64, C). Each block: 64 rows of z vs class c.
// weighted[b,d] = sum_e z[b,e]*cw[c,e,d]; dist = sum_d (weighted-mu[c,d])^2
// writes logk[b*C + c] = -50*dist
__global__ __launch_bounds__(256)
void rbf_kernel(const float* __restrict__ z, const float* __restrict__ cw,
                const float* __restrict__ cent, float* __restrict__ logk) {
    constexpr int BM = 64, BD = 64, BK = 16;
    __shared__ float Zs[BK][BM + 4];
    __shared__ float Ws[BK][BD + 4];
    __shared__ float red[64][17];
    const int tid = threadIdx.x;
    const int tx  = tid & 15;
    const int ty  = tid >> 4;
    const int row0 = blockIdx.x * BM;
    const int c    = blockIdx.y;
    const float* Ac = cw + (size_t)c * E_ * E_;

    float dpart[4] = {0.f, 0.f, 0.f, 0.f};

    for (int d0 = 0; d0 < E_; d0 += BD) {
        float acc[4][4];
        #pragma unroll
        for (int i = 0; i < 4; ++i)
            #pragma unroll
            for (int j = 0; j < 4; ++j) acc[i][j] = 0.f;

        for (int k0 = 0; k0 < E_; k0 += BK) {
            #pragma unroll
            for (int i = 0; i < 4; ++i) {           // 64x16 Z tile (transposed)
                int idx = tid + i * 256;
                int m = idx >> 4, k = idx & 15;
                Zs[k][m] = z[(size_t)(row0 + m) * E_ + k0 + k];
            }
            #pragma unroll
            for (int i = 0; i < 4; ++i) {           // 16x64 cw tile
                int idx = tid + i * 256;
                int k = idx >> 6, n = idx & 63;
                Ws[k][n] = Ac[(size_t)(k0 + k) * E_ + d0 + n];
            }
            __syncthreads();
            #pragma unroll
            for (int kk = 0; kk < BK; ++kk) {
                float af[4], bf[4];
                #pragma unroll
                for (int i = 0; i < 4; ++i) af[i] = Zs[kk][ty * 4 + i];
                #pragma unroll
                for (int j = 0; j < 4; ++j) bf[j] = Ws[kk][tx * 4 + j];
                #pragma unroll
                for (int i = 0; i < 4; ++i)
                    #pragma unroll
                    for (int j = 0; j < 4; ++j)
                        acc[i][j] = fmaf(af[i], bf[j], acc[i][j]);
            }
            __syncthreads();
        }
        // epilogue for this d-tile: accumulate squared distance
        #pragma unroll
        for (int j = 0; j < 4; ++j) {
            float mu = cent[(size_t)c * E_ + d0 + tx * 4 + j];
            #pragma unroll
            for (int i = 0; i < 4; ++i) {
                float d = acc[i][j] - mu;
                dpart[i] = fmaf(d, d, dpart[i]);
            }
        }
    }

    #pragma unroll
    for (int i = 0; i < 4; ++i) red[ty * 4 + i][tx] = dpart[i];
    __syncthreads();
    if (tid < 64) {
        float s = 0.f;
        #pragma unroll
        for (int j = 0; j < 16; ++j) s += red[tid][j];
        logk[(size_t)(row0 + tid) * C_ + c] = NEG_INV_2LS2 * s;
    }
}

// ---------------- softmax + outputs: one wave per row ----------------
__global__ __launch_bounds__(64)
void out_kernel(const float* __restrict__ logk, float* __restrict__ dout) {
    const int b = blockIdx.x;
    const int t = threadIdx.x; // 64
    const float* lr = logk + (size_t)b * C_;
    float v[4];
    float m = -INFINITY;
    #pragma unroll
    for (int i = 0; i < 4; ++i) {
        int idx = t + i * 64;
        v[i] = (idx < C_) ? lr[idx] : -INFINITY;
        m = fmaxf(m, v[i]);
    }
    #pragma unroll
    for (int off = 32; off > 0; off >>= 1) m = fmaxf(m, __shfl_xor(m, off, 64));
    float s = 0.f;
    #pragma unroll
    for (int i = 0; i < 4; ++i) {
        int idx = t + i * 64;
        if (idx < C_) s += expf(v[i] - m);
    }
    #pragma unroll
    for (int off = 32; off > 0; off >>= 1) s += __shfl_xor(s, off, 64);
    const float inv = 1.0f / s;
    #pragma unroll
    for (int i = 0; i < 4; ++i) {
        int idx = t + i * 64;
        if (idx < C_) {
            float p = expf(v[i] - m) * inv;
            dout[(size_t)b * C_ + idx] = p;                       // probs
            dout[(size_t)204800 + (size_t)b * C_ + idx] = p;      // probs[None]
            dout[(size_t)409600 + (size_t)b * C_ + idx] = expf(v[i]); // kernel_vals
        }
    }
    if (t == 0) dout[(size_t)614400 + b] = 1.0f - expf(m);        // uncertainty
}

// ---------------- launcher ----------------
extern "C" void kernel_launch(void* const* d_in, const int* in_sizes, int n_in,
                              void* d_out, int out_size, void* d_ws, size_t ws_size,
                              hipStream_t stream) {
    const float* features = (const float*)d_in[0];
    const float* ln1_g = (const float*)d_in[1];
    const float* ln1_b = (const float*)d_in[2];
    const float* W1    = (const float*)d_in[3];
    const float* b1    = (const float*)d_in[4];
    const float* ln2_g = (const float*)d_in[5];
    const float* ln2_b = (const float*)d_in[6];
    const float* W2    = (const float*)d_in[7];
    const float* b2    = (const float*)d_in[8];
    const float* W3    = (const float*)d_in[9];
    const float* b3    = (const float*)d_in[10];
    const float* cw    = (const float*)d_in[11];
    const float* cent  = (const float*)d_in[12];
    float* out = (float*)d_out;
    float* ws  = (float*)d_ws;

    // Rotating regions, each 1024*2048 floats (8 MB): total 25.2 MB of ws.
    const size_t R = (size_t)B_ * HIDDEN_;
    float* regA = ws;
    float* regB = ws + R;
    float* regC = ws + 2 * R;
    float* h0n = regA;  // [B, EMBED]
    float* h1  = regB;  // [B, HIDDEN]
    float* h1n = regA;  // [B, HIDDEN] (h0n dead)
    float* h2  = regC;  // [B, HIDDEN]
    float* zb  = regA;  // [B, E]      (h1n dead)
    float* lk  = regB;  // [B, C]      (h1 dead)

    ln_kernel<EMBED_><<<B_, 256, 0, stream>>>(features, ln1_g, ln1_b, h0n);

    gemm_kernel<64, 64, 16, 4, 4, 1>
        <<<dim3(HIDDEN_ / 64, B_ / 64), 256, 0, stream>>>(h0n, W1, b1, h1, B_, HIDDEN_, EMBED_);

    ln_kernel<HIDDEN_><<<B_, 256, 0, stream>>>(h1, ln2_g, ln2_b, h1n);

    gemm_kernel<64, 64, 16, 4, 4, 1>
        <<<dim3(HIDDEN_ / 64, B_ / 64), 256, 0, stream>>>(h1n, W2, b2, h2, B_, HIDDEN_, HIDDEN_);

    gemm_kernel<32, 32, 16, 2, 2, 0>
        <<<dim3(E_ / 32, B_ / 32), 256, 0, stream>>>(h2, W3, b3, zb, B_, E_, HIDDEN_);

    rbf_kernel<<<dim3(B_ / 64, C_), 256, 0, stream>>>(zb, cw, cent, lk);

    out_kernel<<<B_, 64, 0, stream>>>(lk, out);
}

// Round 2
// 563.141 us; speedup vs baseline: 1.3668x; 1.3668x over previous
//
#include <hip/hip_runtime.h>
#include <math.h>

// Problem constants (DUQ head)
#define B_      1024
#define EMBED_  768
#define HIDDEN_ 2048
#define C_      200
#define E_      256
#define EPS_    1e-5f
// log_kernel = -dist_sq / (2*0.1^2) = -50*dist_sq
#define NEG_INV_2LS2 (-50.0f)

typedef __attribute__((ext_vector_type(8))) short short8;
typedef __attribute__((ext_vector_type(4))) float f32x4;

__device__ __forceinline__ float gelu_exact(float x) {
    return 0.5f * x * (1.0f + erff(x * 0.70710678118654752f));
}

// round-to-nearest float -> bf16 bits
__device__ __forceinline__ unsigned short f2bf(float x) {
    union { float f; unsigned int u; } v; v.f = x;
    unsigned int r = v.u + 0x7fffu + ((v.u >> 16) & 1u);
    return (unsigned short)(r >> 16);
}
__device__ __forceinline__ float bf2f(unsigned short s) {
    union { float f; unsigned int u; } v; v.u = ((unsigned int)s) << 16;
    return v.f;
}

// async global->LDS, 16B per lane. lds base must be wave-uniform.
__device__ __forceinline__ void glds16(const void* g, void* l) {
    __builtin_amdgcn_global_load_lds(
        (const __attribute__((address_space(1))) unsigned int*)g,
        (__attribute__((address_space(3))) unsigned int*)l, 16, 0, 0);
}

// ---------------- LayerNorm: one block (256 thr) per row ----------------
template<int COLS>
__global__ __launch_bounds__(256)
void ln_kernel(const float* __restrict__ x, const float* __restrict__ g,
               const float* __restrict__ b, float* __restrict__ out) {
    const int row = blockIdx.x;
    const int tid = threadIdx.x;
    constexpr int NT  = 256;
    constexpr int PER = COLS / NT;
    float v[PER];
    float s = 0.f, s2 = 0.f;
    const float* xr = x + (size_t)row * COLS;
    #pragma unroll
    for (int i = 0; i < PER; ++i) {
        v[i] = xr[tid + i * NT];
        s  += v[i];
        s2 += v[i] * v[i];
    }
    #pragma unroll
    for (int off = 32; off > 0; off >>= 1) {
        s  += __shfl_down(s,  off, 64);
        s2 += __shfl_down(s2, off, 64);
    }
    __shared__ float sbuf[4], s2buf[4], stat[2];
    const int wid = tid >> 6;
    if ((tid & 63) == 0) { sbuf[wid] = s; s2buf[wid] = s2; }
    __syncthreads();
    if (tid == 0) {
        float ts = 0.f, ts2 = 0.f;
        #pragma unroll
        for (int i = 0; i < NT / 64; ++i) { ts += sbuf[i]; ts2 += s2buf[i]; }
        float mu  = ts / COLS;
        float var = ts2 / COLS - mu * mu;
        stat[0] = mu;
        stat[1] = rsqrtf(var + EPS_);
    }
    __syncthreads();
    const float mu = stat[0], rstd = stat[1];
    float* orow = out + (size_t)row * COLS;
    #pragma unroll
    for (int i = 0; i < PER; ++i) {
        int c = tid + i * NT;
        orow[c] = (v[i] - mu) * rstd * g[c] + b[c];
    }
}

// ---------------- fp32 GEMM: C = act(A @ W + bias) ----------------
template<int BM, int BN, int BK, int TM, int TN, int ACT>
__global__ __launch_bounds__(256)
void gemm_kernel(const float* __restrict__ A, const float* __restrict__ W,
                 const float* __restrict__ bias, float* __restrict__ Cmat,
                 int M, int N, int K) {
    __shared__ float As[BK][BM + 4];
    __shared__ float Bs[BK][BN + 4];
    const int tid = threadIdx.x;
    const int tx  = tid & 15;
    const int ty  = tid >> 4;
    const int row0 = blockIdx.y * BM;
    const int col0 = blockIdx.x * BN;

    float acc[TM][TN];
    #pragma unroll
    for (int i = 0; i < TM; ++i)
        #pragma unroll
        for (int j = 0; j < TN; ++j) acc[i][j] = 0.f;

    constexpr int A_ELEMS = BM * BK / 256;
    constexpr int B_ELEMS = BK * BN / 256;

    for (int k0 = 0; k0 < K; k0 += BK) {
        #pragma unroll
        for (int i = 0; i < A_ELEMS; ++i) {
            int idx = tid + i * 256;
            int m = idx / BK, k = idx % BK;
            As[k][m] = A[(size_t)(row0 + m) * K + k0 + k];
        }
        #pragma unroll
        for (int i = 0; i < B_ELEMS; ++i) {
            int idx = tid + i * 256;
            int k = idx / BN, n = idx % BN;
            Bs[k][n] = W[(size_t)(k0 + k) * N + col0 + n];
        }
        __syncthreads();
        #pragma unroll
        for (int kk = 0; kk < BK; ++kk) {
            float af[TM], bf[TN];
            #pragma unroll
            for (int i = 0; i < TM; ++i) af[i] = As[kk][ty * TM + i];
            #pragma unroll
            for (int j = 0; j < TN; ++j) bf[j] = Bs[kk][tx * TN + j];
            #pragma unroll
            for (int i = 0; i < TM; ++i)
                #pragma unroll
                for (int j = 0; j < TN; ++j)
                    acc[i][j] = fmaf(af[i], bf[j], acc[i][j]);
        }
        __syncthreads();
    }

    #pragma unroll
    for (int i = 0; i < TM; ++i) {
        int r = row0 + ty * TM + i;
        #pragma unroll
        for (int j = 0; j < TN; ++j) {
            int c = col0 + tx * TN + j;
            float v = acc[i][j] + bias[c];
            if (ACT == 1) v = gelu_exact(v);
            Cmat[(size_t)r * N + c] = v;
        }
    }
}

// ---------------- z -> bf16 hi/lo split ----------------
__global__ __launch_bounds__(256)
void zconv_kernel(const float* __restrict__ z, unsigned short* __restrict__ zh,
                  unsigned short* __restrict__ zl) {
    int i = blockIdx.x * 256 + threadIdx.x;  // grid covers B_*E_
    float x = z[i];
    unsigned short h = f2bf(x);
    zh[i] = h;
    zl[i] = f2bf(x - bf2f(h));
}

// ---------------- cw [c][e][d] fp32 -> cwt hi/lo [c][d][e] bf16 ----------------
__global__ __launch_bounds__(256)
void cwconv_kernel(const float* __restrict__ cw, unsigned short* __restrict__ th,
                   unsigned short* __restrict__ tl) {
    __shared__ float tile[64][65];
    const int c  = blockIdx.x;
    const int t  = blockIdx.y;            // 0..15
    const int e0 = (t >> 2) * 64, d0 = (t & 3) * 64;
    const int tid = threadIdx.x;
    const int col = tid & 63, rr = tid >> 6;  // 4 rows per pass (one per wave)
    const float* src = cw + (size_t)c * 65536 + (size_t)e0 * 256 + d0;
    #pragma unroll
    for (int i = 0; i < 16; ++i) {
        int r = i * 4 + rr;
        tile[r][col] = src[(size_t)r * 256 + col];
    }
    __syncthreads();
    const size_t obase = (size_t)c * 65536 + (size_t)d0 * 256 + e0;
    #pragma unroll
    for (int i = 0; i < 16; ++i) {
        int dl = i * 4 + rr;
        float x = tile[col][dl];          // transposed read, stride-65: conflict-free
        unsigned short h = f2bf(x);
        size_t o = obase + (size_t)dl * 256 + col;
        th[o] = h;
        tl[o] = f2bf(x - bf2f(h));
    }
}

// ---------------- per-class RBF distance via bf16x3 MFMA ----------------
// weighted[64 rows][256 d] = z[64x256] @ cwT, dist to centroid, logk = -50*dist
// Block: 256 thr = 4 waves; wave w owns d-quadrant w*64. K-step 32, 8 steps.
__global__ __launch_bounds__(256)
void rbf_mfma_kernel(const unsigned short* __restrict__ zh,
                     const unsigned short* __restrict__ zl,
                     const unsigned short* __restrict__ cwh,
                     const unsigned short* __restrict__ cwl,
                     const float* __restrict__ cent,
                     float* __restrict__ logk) {
    __shared__ short Ah[64 * 32], Al[64 * 32];       // 4KB + 4KB  [row][k]
    __shared__ short Bh[256 * 32], Bl[256 * 32];     // 16KB + 16KB [d][k]
    __shared__ float red[64][4];

    const int tid  = threadIdx.x;
    const int lane = tid & 63;
    const int w    = tid >> 6;
    const int fr   = lane & 15;   // fragment row/col index
    const int fg   = lane >> 4;   // k-group

    // XCD-chunked swizzle: 3200 blocks, 8 XCDs, 400 per chunk (3200%8==0)
    const int bid = blockIdx.x;
    const int wg  = (bid & 7) * 400 + (bid >> 3);
    const int c    = wg >> 4;          // class, consecutive within a chunk
    const int row0 = (wg & 15) * 64;   // z row block

    // per-lane global staging addresses (16B per lane)
    const int srow = tid >> 2;               // 0..63 : A row / B d-subrow
    const int skel = (tid & 3) * 8;          // k element offset within 32
    const unsigned short* gAh = zh + (size_t)(row0 + srow) * E_ + skel;
    const unsigned short* gAl = zl + (size_t)(row0 + srow) * E_ + skel;
    const unsigned short* gBh = cwh + (size_t)c * 65536 + (size_t)srow * E_ + skel;
    const unsigned short* gBl = cwl + (size_t)c * 65536 + (size_t)srow * E_ + skel;
    // wave-uniform LDS staging bases (shorts)
    short* lA = &((short*)Ah)[w * 512];
    short* lB0 = (short*)Bh;
    short* lB1 = (short*)Bl;

    f32x4 acc[4][4];
    #pragma unroll
    for (int m = 0; m < 4; ++m)
        #pragma unroll
        for (int n = 0; n < 4; ++n)
            acc[m][n] = (f32x4){0.f, 0.f, 0.f, 0.f};

    for (int k0 = 0; k0 < 8; ++k0) {          // k element offset = k0*32
        const int ke = k0 * 32;
        glds16(gAh + ke, &Ah[w * 512]);
        glds16(gAl + ke, &Al[w * 512]);
        #pragma unroll
        for (int i = 0; i < 4; ++i) {
            glds16(gBh + (size_t)i * 64 * E_ + ke, &Bh[i * 2048 + w * 512]);
            glds16(gBl + (size_t)i * 64 * E_ + ke, &Bl[i * 2048 + w * 512]);
        }
        __syncthreads();   // drains vmcnt before barrier

        short8 bh[4], bl[4];
        #pragma unroll
        for (int n = 0; n < 4; ++n) {
            int d = w * 64 + n * 16 + fr;
            bh[n] = *(const short8*)&Bh[d * 32 + fg * 8];
            bl[n] = *(const short8*)&Bl[d * 32 + fg * 8];
        }
        #pragma unroll
        for (int m = 0; m < 4; ++m) {
            int r = m * 16 + fr;
            short8 ah = *(const short8*)&Ah[r * 32 + fg * 8];
            short8 al = *(const short8*)&Al[r * 32 + fg * 8];
            #pragma unroll
            for (int n = 0; n < 4; ++n) {
                acc[m][n] = __builtin_amdgcn_mfma_f32_16x16x32_bf16(ah, bh[n], acc[m][n], 0, 0, 0);
                acc[m][n] = __builtin_amdgcn_mfma_f32_16x16x32_bf16(ah, bl[n], acc[m][n], 0, 0, 0);
                acc[m][n] = __builtin_amdgcn_mfma_f32_16x16x32_bf16(al, bh[n], acc[m][n], 0, 0, 0);
            }
        }
        __syncthreads();
    }

    // epilogue: dist_sq per row
    float cmu[4];
    #pragma unroll
    for (int n = 0; n < 4; ++n) cmu[n] = cent[(size_t)c * E_ + w * 64 + n * 16 + fr];

    #pragma unroll
    for (int m = 0; m < 4; ++m) {
        #pragma unroll
        for (int r = 0; r < 4; ++r) {
            float p = 0.f;
            #pragma unroll
            for (int n = 0; n < 4; ++n) {
                float d = acc[m][n][r] - cmu[n];
                p = fmaf(d, d, p);
            }
            // reduce over the 16 lanes (fr) holding different cols of this row
            p += __shfl_xor(p, 1, 64);
            p += __shfl_xor(p, 2, 64);
            p += __shfl_xor(p, 4, 64);
            p += __shfl_xor(p, 8, 64);
            if (fr == 0) red[m * 16 + fg * 4 + r][w] = p;
        }
    }
    __syncthreads();
    if (tid < 64) {
        float s = red[tid][0] + red[tid][1] + red[tid][2] + red[tid][3];
        logk[(size_t)(row0 + tid) * C_ + c] = NEG_INV_2LS2 * s;
    }
}

// ---------------- softmax + outputs: one wave per row ----------------
__global__ __launch_bounds__(64)
void out_kernel(const float* __restrict__ logk, float* __restrict__ dout) {
    const int b = blockIdx.x;
    const int t = threadIdx.x; // 64
    const float* lr = logk + (size_t)b * C_;
    float v[4];
    float m = -INFINITY;
    #pragma unroll
    for (int i = 0; i < 4; ++i) {
        int idx = t + i * 64;
        v[i] = (idx < C_) ? lr[idx] : -INFINITY;
        m = fmaxf(m, v[i]);
    }
    #pragma unroll
    for (int off = 32; off > 0; off >>= 1) m = fmaxf(m, __shfl_xor(m, off, 64));
    float s = 0.f;
    #pragma unroll
    for (int i = 0; i < 4; ++i) {
        int idx = t + i * 64;
        if (idx < C_) s += expf(v[i] - m);
    }
    #pragma unroll
    for (int off = 32; off > 0; off >>= 1) s += __shfl_xor(s, off, 64);
    const float inv = 1.0f / s;
    #pragma unroll
    for (int i = 0; i < 4; ++i) {
        int idx = t + i * 64;
        if (idx < C_) {
            float p = expf(v[i] - m) * inv;
            dout[(size_t)b * C_ + idx] = p;
            dout[(size_t)204800 + (size_t)b * C_ + idx] = p;
            dout[(size_t)409600 + (size_t)b * C_ + idx] = expf(v[i]);
        }
    }
    if (t == 0) dout[(size_t)614400 + b] = 1.0f - expf(m);
}

// ---------------- launcher ----------------
extern "C" void kernel_launch(void* const* d_in, const int* in_sizes, int n_in,
                              void* d_out, int out_size, void* d_ws, size_t ws_size,
                              hipStream_t stream) {
    const float* features = (const float*)d_in[0];
    const float* ln1_g = (const float*)d_in[1];
    const float* ln1_b = (const float*)d_in[2];
    const float* W1    = (const float*)d_in[3];
    const float* b1    = (const float*)d_in[4];
    const float* ln2_g = (const float*)d_in[5];
    const float* ln2_b = (const float*)d_in[6];
    const float* W2    = (const float*)d_in[7];
    const float* b2    = (const float*)d_in[8];
    const float* W3    = (const float*)d_in[9];
    const float* b3    = (const float*)d_in[10];
    const float* cw    = (const float*)d_in[11];
    const float* cent  = (const float*)d_in[12];
    float* out = (float*)d_out;
    float* ws  = (float*)d_ws;

    // fp32 rotating regions (8 MB each)
    const size_t R = (size_t)B_ * HIDDEN_;
    float* regA = ws;
    float* regB = ws + R;
    float* regC = ws + 2 * R;
    float* h0n = regA;  // [B, EMBED]
    float* h1  = regB;  // [B, HIDDEN]
    float* h1n = regA;  // [B, HIDDEN]
    float* h2  = regC;  // [B, HIDDEN]
    float* zb  = regA;  // [B, E]
    float* lk  = regB;  // [B, C]

    // bf16 split regions after the fp32 ones
    unsigned short* zh  = (unsigned short*)(ws + 3 * R);
    unsigned short* zl  = zh + (size_t)B_ * E_;
    unsigned short* cwh = zl + (size_t)B_ * E_;
    unsigned short* cwl = cwh + (size_t)C_ * E_ * E_;

    // cw conversion first (depends only on inputs)
    cwconv_kernel<<<dim3(C_, 16), 256, 0, stream>>>(cw, cwh, cwl);

    ln_kernel<EMBED_><<<B_, 256, 0, stream>>>(features, ln1_g, ln1_b, h0n);

    gemm_kernel<64, 64, 16, 4, 4, 1>
        <<<dim3(HIDDEN_ / 64, B_ / 64), 256, 0, stream>>>(h0n, W1, b1, h1, B_, HIDDEN_, EMBED_);

    ln_kernel<HIDDEN_><<<B_, 256, 0, stream>>>(h1, ln2_g, ln2_b, h1n);

    gemm_kernel<64, 64, 16, 4, 4, 1>
        <<<dim3(HIDDEN_ / 64, B_ / 64), 256, 0, stream>>>(h1n, W2, b2, h2, B_, HIDDEN_, HIDDEN_);

    gemm_kernel<32, 32, 16, 2, 2, 0>
        <<<dim3(E_ / 32, B_ / 32), 256, 0, stream>>>(h2, W3, b3, zb, B_, E_, HIDDEN_);

    zconv_kernel<<<(B_ * E_) / 256, 256, 0, stream>>>(zb, zh, zl);

    rbf_mfma_kernel<<<3200, 256, 0, stream>>>(zh, zl, cwh, cwl, cent, lk);

    out_kernel<<<B_, 64, 0, stream>>>(lk, out);
}

// Round 8
// 341.531 us; speedup vs baseline: 2.2537x; 1.6489x over previous
//
#include <hip/hip_runtime.h>
#include <math.h>

// Problem constants (DUQ head)
#define B_      1024
#define EMBED_  768
#define HIDDEN_ 2048
#define C_      200
#define E_      256
#define EPS_    1e-5f
#define NEG_INV_2LS2 (-50.0f)

typedef unsigned short ushort_t;
typedef __attribute__((ext_vector_type(8))) short short8;
typedef __attribute__((ext_vector_type(4))) float f32x4;

__device__ __forceinline__ float gelu_exact(float x) {
    return 0.5f * x * (1.0f + erff(x * 0.70710678118654752f));
}

// round-to-nearest-even float -> bf16 bits
__device__ __forceinline__ ushort_t f2bf(float x) {
    union { float f; unsigned int u; } v; v.f = x;
    unsigned int r = v.u + 0x7fffu + ((v.u >> 16) & 1u);
    return (ushort_t)(r >> 16);
}
__device__ __forceinline__ float bf2f(ushort_t s) {
    union { float f; unsigned int u; } v; v.u = ((unsigned int)s) << 16;
    return v.f;
}

// async global->LDS, 16B per lane; lds base must be wave-uniform.
__device__ __forceinline__ void glds16(const void* g, void* l) {
    __builtin_amdgcn_global_load_lds(
        (const __attribute__((address_space(1))) unsigned int*)g,
        (__attribute__((address_space(3))) unsigned int*)l, 16, 0, 0);
}

// ---------------- LayerNorm -> split bf16 (hi/lo) ----------------
template<int COLS>
__global__ __launch_bounds__(256)
void ln_split_kernel(const float* __restrict__ x, const float* __restrict__ g,
                     const float* __restrict__ b, ushort_t* __restrict__ oh,
                     ushort_t* __restrict__ ol) {
    const int row = blockIdx.x;
    const int tid = threadIdx.x;
    constexpr int NT  = 256;
    constexpr int PER = COLS / NT;
    float v[PER];
    float s = 0.f, s2 = 0.f;
    const float* xr = x + (size_t)row * COLS;
    #pragma unroll
    for (int i = 0; i < PER; ++i) {
        v[i] = xr[tid + i * NT];
        s  += v[i];
        s2 += v[i] * v[i];
    }
    #pragma unroll
    for (int off = 32; off > 0; off >>= 1) {
        s  += __shfl_down(s,  off, 64);
        s2 += __shfl_down(s2, off, 64);
    }
    __shared__ float sbuf[4], s2buf[4], stat[2];
    const int wid = tid >> 6;
    if ((tid & 63) == 0) { sbuf[wid] = s; s2buf[wid] = s2; }
    __syncthreads();
    if (tid == 0) {
        float ts = 0.f, ts2 = 0.f;
        #pragma unroll
        for (int i = 0; i < NT / 64; ++i) { ts += sbuf[i]; ts2 += s2buf[i]; }
        float mu  = ts / COLS;
        float var = ts2 / COLS - mu * mu;
        stat[0] = mu;
        stat[1] = rsqrtf(var + EPS_);
    }
    __syncthreads();
    const float mu = stat[0], rstd = stat[1];
    #pragma unroll
    for (int i = 0; i < PER; ++i) {
        int c = tid + i * NT;
        float y = (v[i] - mu) * rstd * g[c] + b[c];
        ushort_t h = f2bf(y);
        size_t o = (size_t)row * COLS + c;
        oh[o] = h;
        ol[o] = f2bf(y - bf2f(h));
    }
}

// ---------------- transpose + hi/lo split: src [R][Nc] fp32 -> out [Nc][R] bf16 ----
// grid (batch, (R/64)*(Nc/64)); batch stride R*Nc on both sides.
__global__ __launch_bounds__(256)
void tconv_kernel(const float* __restrict__ src, ushort_t* __restrict__ th,
                  ushort_t* __restrict__ tl, int R, int Nc) {
    __shared__ float tile[64][65];
    const size_t base = (size_t)blockIdx.x * R * Nc;
    const int ntx = Nc >> 6;
    const int ky = blockIdx.y / ntx, nx = blockIdx.y % ntx;
    const int tid = threadIdx.x;
    const int col = tid & 63, rr = tid >> 6;
    const float* s = src + base + (size_t)(ky * 64) * Nc + nx * 64;
    #pragma unroll
    for (int i = 0; i < 16; ++i) {
        int r = i * 4 + rr;
        tile[r][col] = s[(size_t)r * Nc + col];
    }
    __syncthreads();
    #pragma unroll
    for (int i = 0; i < 16; ++i) {
        int dl = i * 4 + rr;
        float x = tile[col][dl];            // stride-65 read: conflict-free
        ushort_t h = f2bf(x);
        size_t o = base + (size_t)(nx * 64 + dl) * R + ky * 64 + col;
        th[o] = h;
        tl[o] = f2bf(x - bf2f(h));
    }
}

// ---------------- bf16x3 MFMA GEMM: out = act(A @ W + bias) ----------------
// A split [M][K], W split pre-transposed [N][K]. Tile BM x 64, BK=64, 4 waves 2x2.
// LDS slot-XOR swizzle (rule 21): linear glds dest + inverse-swizzled global src.
template<int MREP, int ACT, int OUT_SPLIT>
__global__ __launch_bounds__(256)
void mfma_gemm_kernel(const ushort_t* __restrict__ Ah, const ushort_t* __restrict__ Al,
                      const ushort_t* __restrict__ Wh, const ushort_t* __restrict__ Wl,
                      const float* __restrict__ bias,
                      float* __restrict__ outF, ushort_t* __restrict__ Oh,
                      ushort_t* __restrict__ Ol, int M, int N, int K) {
    constexpr int BM = MREP * 32;
    __shared__ short AsH[BM * 64], AsL[BM * 64];
    __shared__ short BsH[64 * 64], BsL[64 * 64];
    const int tid  = threadIdx.x;
    const int lane = tid & 63;
    const int w    = tid >> 6;
    const int wr = w >> 1, wc = w & 1;
    const int fr = lane & 15, fg = lane >> 4;

    // XCD-chunked 1D swizzle (nblk % 8 == 0), B-panel-major decomposition
    const int nblk = gridDim.x, chunk = nblk >> 3;
    const int wg = (blockIdx.x & 7) * chunk + (blockIdx.x >> 3);
    const int gy = M / BM;
    const int cx = wg / gy, ry = wg % gy;
    const int row0 = ry * BM, col0 = cx * 64;

    // staging lane mapping: row = p*32 + (tid>>3), slot = tid&7, source slot
    // pre-swizzled so LDS[row][s] = global[row][s ^ (row&7)]
    const int srow  = tid >> 3;
    const int sslot = (tid & 7) ^ (srow & 7);
    const size_t aoff = (size_t)(row0 + srow) * K + sslot * 8;
    const size_t boff = (size_t)(col0 + srow) * K + sslot * 8;

    f32x4 acc[MREP][2];
    #pragma unroll
    for (int m = 0; m < MREP; ++m)
        #pragma unroll
        for (int n = 0; n < 2; ++n) acc[m][n] = (f32x4){0.f, 0.f, 0.f, 0.f};

    for (int k0 = 0; k0 < K; k0 += 64) {
        #pragma unroll
        for (int p = 0; p < BM / 32; ++p) {
            glds16(Ah + aoff + (size_t)p * 32 * K + k0, &AsH[p * 2048 + w * 512]);
            glds16(Al + aoff + (size_t)p * 32 * K + k0, &AsL[p * 2048 + w * 512]);
        }
        #pragma unroll
        for (int p = 0; p < 2; ++p) {
            glds16(Wh + boff + (size_t)p * 32 * K + k0, &BsH[p * 2048 + w * 512]);
            glds16(Wl + boff + (size_t)p * 32 * K + k0, &BsL[p * 2048 + w * 512]);
        }
        __syncthreads();
        #pragma unroll
        for (int ks = 0; ks < 2; ++ks) {
            short8 bh[2], bl[2];
            #pragma unroll
            for (int n = 0; n < 2; ++n) {
                int rB = wc * 32 + n * 16 + fr;
                int sl = ((ks * 4 + fg) ^ (rB & 7)) << 3;
                bh[n] = *(const short8*)&BsH[rB * 64 + sl];
                bl[n] = *(const short8*)&BsL[rB * 64 + sl];
            }
            #pragma unroll
            for (int m = 0; m < MREP; ++m) {
                int rA = wr * MREP * 16 + m * 16 + fr;
                int sl = ((ks * 4 + fg) ^ (rA & 7)) << 3;
                short8 ah = *(const short8*)&AsH[rA * 64 + sl];
                short8 al = *(const short8*)&AsL[rA * 64 + sl];
                #pragma unroll
                for (int n = 0; n < 2; ++n) {
                    acc[m][n] = __builtin_amdgcn_mfma_f32_16x16x32_bf16(ah, bh[n], acc[m][n], 0, 0, 0);
                    acc[m][n] = __builtin_amdgcn_mfma_f32_16x16x32_bf16(ah, bl[n], acc[m][n], 0, 0, 0);
                    acc[m][n] = __builtin_amdgcn_mfma_f32_16x16x32_bf16(al, bh[n], acc[m][n], 0, 0, 0);
                }
            }
        }
        __syncthreads();
    }

    #pragma unroll
    for (int n = 0; n < 2; ++n) {
        int col = col0 + wc * 32 + n * 16 + fr;
        float bv = bias[col];
        #pragma unroll
        for (int m = 0; m < MREP; ++m) {
            #pragma unroll
            for (int r = 0; r < 4; ++r) {
                int row = row0 + wr * MREP * 16 + m * 16 + fg * 4 + r;
                float v = acc[m][n][r] + bv;
                if (ACT) v = gelu_exact(v);
                size_t o = (size_t)row * N + col;
                if (OUT_SPLIT) {
                    ushort_t h = f2bf(v);
                    Oh[o] = h;
                    Ol[o] = f2bf(v - bf2f(h));
                } else {
                    outF[o] = v;
                }
            }
        }
    }
}

// ---------------- per-class RBF distance via bf16x3 MFMA ----------------
__global__ __launch_bounds__(256)
void rbf_mfma_kernel(const ushort_t* __restrict__ zh,
                     const ushort_t* __restrict__ zl,
                     const ushort_t* __restrict__ cwh,
                     const ushort_t* __restrict__ cwl,
                     const float* __restrict__ cent,
                     float* __restrict__ logk) {
    __shared__ short Ah[64 * 32], Al[64 * 32];
    __shared__ short Bh[256 * 32], Bl[256 * 32];
    __shared__ float red[64][4];

    const int tid  = threadIdx.x;
    const int lane = tid & 63;
    const int w    = tid >> 6;
    const int fr   = lane & 15;
    const int fg   = lane >> 4;

    const int bid = blockIdx.x;
    const int wg  = (bid & 7) * 400 + (bid >> 3);
    const int c    = wg >> 4;
    const int row0 = (wg & 15) * 64;

    // staging: row = tid>>2, slot = tid&3; inverse-swizzled global source
    const int srow = tid >> 2;
    const int sw   = ((tid & 3) ^ (srow & 3)) * 8;
    const ushort_t* gAh = zh + (size_t)(row0 + srow) * E_ + sw;
    const ushort_t* gAl = zl + (size_t)(row0 + srow) * E_ + sw;
    const ushort_t* gBh = cwh + (size_t)c * 65536 + (size_t)srow * E_ + sw;
    const ushort_t* gBl = cwl + (size_t)c * 65536 + (size_t)srow * E_ + sw;

    f32x4 acc[4][4];
    #pragma unroll
    for (int m = 0; m < 4; ++m)
        #pragma unroll
        for (int n = 0; n < 4; ++n)
            acc[m][n] = (f32x4){0.f, 0.f, 0.f, 0.f};

    for (int k0 = 0; k0 < 8; ++k0) {
        const int ke = k0 * 32;
        glds16(gAh + ke, &Ah[w * 512]);
        glds16(gAl + ke, &Al[w * 512]);
        #pragma unroll
        for (int i = 0; i < 4; ++i) {
            glds16(gBh + (size_t)i * 64 * E_ + ke, &Bh[i * 2048 + w * 512]);
            glds16(gBl + (size_t)i * 64 * E_ + ke, &Bl[i * 2048 + w * 512]);
        }
        __syncthreads();

        short8 bh[4], bl[4];
        #pragma unroll
        for (int n = 0; n < 4; ++n) {
            int d = w * 64 + n * 16 + fr;
            int sl = (fg ^ (d & 3)) << 3;
            bh[n] = *(const short8*)&Bh[d * 32 + sl];
            bl[n] = *(const short8*)&Bl[d * 32 + sl];
        }
        #pragma unroll
        for (int m = 0; m < 4; ++m) {
            int r = m * 16 + fr;
            int sa = (fg ^ (r & 3)) << 3;
            short8 ah = *(const short8*)&Ah[r * 32 + sa];
            short8 al = *(const short8*)&Al[r * 32 + sa];
            #pragma unroll
            for (int n = 0; n < 4; ++n) {
                acc[m][n] = __builtin_amdgcn_mfma_f32_16x16x32_bf16(ah, bh[n], acc[m][n], 0, 0, 0);
                acc[m][n] = __builtin_amdgcn_mfma_f32_16x16x32_bf16(ah, bl[n], acc[m][n], 0, 0, 0);
                acc[m][n] = __builtin_amdgcn_mfma_f32_16x16x32_bf16(al, bh[n], acc[m][n], 0, 0, 0);
            }
        }
        __syncthreads();
    }

    float cmu[4];
    #pragma unroll
    for (int n = 0; n < 4; ++n) cmu[n] = cent[(size_t)c * E_ + w * 64 + n * 16 + fr];

    #pragma unroll
    for (int m = 0; m < 4; ++m) {
        #pragma unroll
        for (int r = 0; r < 4; ++r) {
            float p = 0.f;
            #pragma unroll
            for (int n = 0; n < 4; ++n) {
                float d = acc[m][n][r] - cmu[n];
                p = fmaf(d, d, p);
            }
            p += __shfl_xor(p, 1, 64);
            p += __shfl_xor(p, 2, 64);
            p += __shfl_xor(p, 4, 64);
            p += __shfl_xor(p, 8, 64);
            if (fr == 0) red[m * 16 + fg * 4 + r][w] = p;
        }
    }
    __syncthreads();
    if (tid < 64) {
        float s = red[tid][0] + red[tid][1] + red[tid][2] + red[tid][3];
        logk[(size_t)(row0 + tid) * C_ + c] = NEG_INV_2LS2 * s;
    }
}

// ---------------- softmax + outputs ----------------
__global__ __launch_bounds__(64)
void out_kernel(const float* __restrict__ logk, float* __restrict__ dout) {
    const int b = blockIdx.x;
    const int t = threadIdx.x;
    const float* lr = logk + (size_t)b * C_;
    float v[4];
    float m = -INFINITY;
    #pragma unroll
    for (int i = 0; i < 4; ++i) {
        int idx = t + i * 64;
        v[i] = (idx < C_) ? lr[idx] : -INFINITY;
        m = fmaxf(m, v[i]);
    }
    #pragma unroll
    for (int off = 32; off > 0; off >>= 1) m = fmaxf(m, __shfl_xor(m, off, 64));
    float s = 0.f;
    #pragma unroll
    for (int i = 0; i < 4; ++i) {
        int idx = t + i * 64;
        if (idx < C_) s += expf(v[i] - m);
    }
    #pragma unroll
    for (int off = 32; off > 0; off >>= 1) s += __shfl_xor(s, off, 64);
    const float inv = 1.0f / s;
    #pragma unroll
    for (int i = 0; i < 4; ++i) {
        int idx = t + i * 64;
        if (idx < C_) {
            float p = expf(v[i] - m) * inv;
            dout[(size_t)b * C_ + idx] = p;
            dout[(size_t)204800 + (size_t)b * C_ + idx] = p;
            dout[(size_t)409600 + (size_t)b * C_ + idx] = expf(v[i]);
        }
    }
    if (t == 0) dout[(size_t)614400 + b] = 1.0f - expf(m);
}

// ---------------- launcher ----------------
extern "C" void kernel_launch(void* const* d_in, const int* in_sizes, int n_in,
                              void* d_out, int out_size, void* d_ws, size_t ws_size,
                              hipStream_t stream) {
    const float* features = (const float*)d_in[0];
    const float* ln1_g = (const float*)d_in[1];
    const float* ln1_b = (const float*)d_in[2];
    const float* W1    = (const float*)d_in[3];
    const float* b1    = (const float*)d_in[4];
    const float* ln2_g = (const float*)d_in[5];
    const float* ln2_b = (const float*)d_in[6];
    const float* W2    = (const float*)d_in[7];
    const float* b2    = (const float*)d_in[8];
    const float* W3    = (const float*)d_in[9];
    const float* b3    = (const float*)d_in[10];
    const float* cw    = (const float*)d_in[11];
    const float* cent  = (const float*)d_in[12];
    float* out = (float*)d_out;
    float* ws  = (float*)d_ws;

    // fp32 scratch
    float* h1 = ws;                       // [B, HIDDEN] = 2,097,152 floats
    float* lk = ws + 2097152;             // [B, C] = 204,800 floats
    // bf16 split scratch (16B-aligned: (2097152+204800)*4 is divisible by 16)
    ushort_t* u = (ushort_t*)(ws + 2097152 + 204800);
    size_t o = 0;
    ushort_t* h0h = u + o; o += (size_t)B_ * EMBED_;
    ushort_t* h0l = u + o; o += (size_t)B_ * EMBED_;
    ushort_t* h1h = u + o; o += (size_t)B_ * HIDDEN_;
    ushort_t* h1l = u + o; o += (size_t)B_ * HIDDEN_;
    ushort_t* h2h = u + o; o += (size_t)B_ * HIDDEN_;
    ushort_t* h2l = u + o; o += (size_t)B_ * HIDDEN_;
    ushort_t* zh  = u + o; o += (size_t)B_ * E_;
    ushort_t* zl  = u + o; o += (size_t)B_ * E_;
    ushort_t* w1h = u + o; o += (size_t)EMBED_ * HIDDEN_;
    ushort_t* w1l = u + o; o += (size_t)EMBED_ * HIDDEN_;
    ushort_t* w2h = u + o; o += (size_t)HIDDEN_ * HIDDEN_;
    ushort_t* w2l = u + o; o += (size_t)HIDDEN_ * HIDDEN_;
    ushort_t* w3h = u + o; o += (size_t)HIDDEN_ * E_;
    ushort_t* w3l = u + o; o += (size_t)HIDDEN_ * E_;
    ushort_t* cwh = u + o; o += (size_t)C_ * E_ * E_;
    ushort_t* cwl = u + o; o += (size_t)C_ * E_ * E_;

    // weight conversions (input-only dependencies) first
    tconv_kernel<<<dim3(C_, 16), 256, 0, stream>>>(cw, cwh, cwl, E_, E_);
    tconv_kernel<<<dim3(1, (EMBED_ / 64) * (HIDDEN_ / 64)), 256, 0, stream>>>(W1, w1h, w1l, EMBED_, HIDDEN_);
    tconv_kernel<<<dim3(1, (HIDDEN_ / 64) * (HIDDEN_ / 64)), 256, 0, stream>>>(W2, w2h, w2l, HIDDEN_, HIDDEN_);
    tconv_kernel<<<dim3(1, (HIDDEN_ / 64) * (E_ / 64)), 256, 0, stream>>>(W3, w3h, w3l, HIDDEN_, E_);

    ln_split_kernel<EMBED_><<<B_, 256, 0, stream>>>(features, ln1_g, ln1_b, h0h, h0l);

    mfma_gemm_kernel<2, 1, 0><<<(HIDDEN_ / 64) * (B_ / 64), 256, 0, stream>>>(
        h0h, h0l, w1h, w1l, b1, h1, nullptr, nullptr, B_, HIDDEN_, EMBED_);

    ln_split_kernel<HIDDEN_><<<B_, 256, 0, stream>>>(h1, ln2_g, ln2_b, h1h, h1l);

    mfma_gemm_kernel<2, 1, 1><<<(HIDDEN_ / 64) * (B_ / 64), 256, 0, stream>>>(
        h1h, h1l, w2h, w2l, b2, nullptr, h2h, h2l, B_, HIDDEN_, HIDDEN_);

    mfma_gemm_kernel<1, 0, 1><<<(E_ / 64) * (B_ / 32), 256, 0, stream>>>(
        h2h, h2l, w3h, w3l, b3, nullptr, zh, zl, B_, E_, HIDDEN_);

    rbf_mfma_kernel<<<3200, 256, 0, stream>>>(zh, zl, cwh, cwl, cent, lk);

    out_kernel<<<B_, 64, 0, stream>>>(lk, out);
}

// Round 11
// 320.485 us; speedup vs baseline: 2.4017x; 1.0657x over previous
//
#include <hip/hip_runtime.h>
#include <math.h>

// Problem constants (DUQ head)
#define B_      1024
#define EMBED_  768
#define HIDDEN_ 2048
#define C_      200
#define E_      256
#define EPS_    1e-5f
#define NEG_INV_2LS2 (-50.0f)

typedef unsigned short ushort_t;
typedef __attribute__((ext_vector_type(8))) short short8;
typedef __attribute__((ext_vector_type(4))) float f32x4;

__device__ __forceinline__ float gelu_exact(float x) {
    return 0.5f * x * (1.0f + erff(x * 0.70710678118654752f));
}

// round-to-nearest-even float -> bf16 bits
__device__ __forceinline__ ushort_t f2bf(float x) {
    union { float f; unsigned int u; } v; v.f = x;
    unsigned int r = v.u + 0x7fffu + ((v.u >> 16) & 1u);
    return (ushort_t)(r >> 16);
}
__device__ __forceinline__ float bf2f(ushort_t s) {
    union { float f; unsigned int u; } v; v.u = ((unsigned int)s) << 16;
    return v.f;
}

// async global->LDS, 16B per lane; lds base must be wave-uniform.
__device__ __forceinline__ void glds16(const void* g, void* l) {
    __builtin_amdgcn_global_load_lds(
        (const __attribute__((address_space(1))) unsigned int*)g,
        (__attribute__((address_space(3))) unsigned int*)l, 16, 0, 0);
}

// ---------------- LayerNorm -> split bf16 (hi/lo) ----------------
template<int COLS>
__global__ __launch_bounds__(256)
void ln_split_kernel(const float* __restrict__ x, const float* __restrict__ g,
                     const float* __restrict__ b, ushort_t* __restrict__ oh,
                     ushort_t* __restrict__ ol) {
    const int row = blockIdx.x;
    const int tid = threadIdx.x;
    constexpr int NT  = 256;
    constexpr int PER = COLS / NT;
    float v[PER];
    float s = 0.f, s2 = 0.f;
    const float* xr = x + (size_t)row * COLS;
    #pragma unroll
    for (int i = 0; i < PER; ++i) {
        v[i] = xr[tid + i * NT];
        s  += v[i];
        s2 += v[i] * v[i];
    }
    #pragma unroll
    for (int off = 32; off > 0; off >>= 1) {
        s  += __shfl_down(s,  off, 64);
        s2 += __shfl_down(s2, off, 64);
    }
    __shared__ float sbuf[4], s2buf[4], stat[2];
    const int wid = tid >> 6;
    if ((tid & 63) == 0) { sbuf[wid] = s; s2buf[wid] = s2; }
    __syncthreads();
    if (tid == 0) {
        float ts = 0.f, ts2 = 0.f;
        #pragma unroll
        for (int i = 0; i < NT / 64; ++i) { ts += sbuf[i]; ts2 += s2buf[i]; }
        float mu  = ts / COLS;
        float var = ts2 / COLS - mu * mu;
        stat[0] = mu;
        stat[1] = rsqrtf(var + EPS_);
    }
    __syncthreads();
    const float mu = stat[0], rstd = stat[1];
    #pragma unroll
    for (int i = 0; i < PER; ++i) {
        int c = tid + i * NT;
        float y = (v[i] - mu) * rstd * g[c] + b[c];
        ushort_t h = f2bf(y);
        size_t o = (size_t)row * COLS + c;
        oh[o] = h;
        ol[o] = f2bf(y - bf2f(h));
    }
}

// ---------------- transpose + hi/lo split: src [R][Nc] fp32 -> out [Nc][R] bf16 ----
__global__ __launch_bounds__(256)
void tconv_kernel(const float* __restrict__ src, ushort_t* __restrict__ th,
                  ushort_t* __restrict__ tl, int R, int Nc) {
    __shared__ float tile[64][65];
    const size_t base = (size_t)blockIdx.x * R * Nc;
    const int ntx = Nc >> 6;
    const int ky = blockIdx.y / ntx, nx = blockIdx.y % ntx;
    const int tid = threadIdx.x;
    const int col = tid & 63, rr = tid >> 6;
    const float* s = src + base + (size_t)(ky * 64) * Nc + nx * 64;
    #pragma unroll
    for (int i = 0; i < 16; ++i) {
        int r = i * 4 + rr;
        tile[r][col] = s[(size_t)r * Nc + col];
    }
    __syncthreads();
    #pragma unroll
    for (int i = 0; i < 16; ++i) {
        int dl = i * 4 + rr;
        float x = tile[col][dl];            // stride-65 read: conflict-free
        ushort_t h = f2bf(x);
        size_t o = base + (size_t)(nx * 64 + dl) * R + ky * 64 + col;
        th[o] = h;
        tl[o] = f2bf(x - bf2f(h));
    }
}

// ---------------- bf16x3 MFMA GEMM: out = act(A @ W + bias) ----------------
// (unchanged from round 8 — rows are 128B with XOR-8, conflict-free)
template<int MREP, int ACT, int OUT_SPLIT>
__global__ __launch_bounds__(256)
void mfma_gemm_kernel(const ushort_t* __restrict__ Ah, const ushort_t* __restrict__ Al,
                      const ushort_t* __restrict__ Wh, const ushort_t* __restrict__ Wl,
                      const float* __restrict__ bias,
                      float* __restrict__ outF, ushort_t* __restrict__ Oh,
                      ushort_t* __restrict__ Ol, int M, int N, int K) {
    constexpr int BM = MREP * 32;
    __shared__ short AsH[BM * 64], AsL[BM * 64];
    __shared__ short BsH[64 * 64], BsL[64 * 64];
    const int tid  = threadIdx.x;
    const int lane = tid & 63;
    const int w    = tid >> 6;
    const int wr = w >> 1, wc = w & 1;
    const int fr = lane & 15, fg = lane >> 4;

    const int nblk = gridDim.x, chunk = nblk >> 3;
    const int wg = (blockIdx.x & 7) * chunk + (blockIdx.x >> 3);
    const int gy = M / BM;
    const int cx = wg / gy, ry = wg % gy;
    const int row0 = ry * BM, col0 = cx * 64;

    const int srow  = tid >> 3;
    const int sslot = (tid & 7) ^ (srow & 7);
    const size_t aoff = (size_t)(row0 + srow) * K + sslot * 8;
    const size_t boff = (size_t)(col0 + srow) * K + sslot * 8;

    f32x4 acc[MREP][2];
    #pragma unroll
    for (int m = 0; m < MREP; ++m)
        #pragma unroll
        for (int n = 0; n < 2; ++n) acc[m][n] = (f32x4){0.f, 0.f, 0.f, 0.f};

    for (int k0 = 0; k0 < K; k0 += 64) {
        #pragma unroll
        for (int p = 0; p < BM / 32; ++p) {
            glds16(Ah + aoff + (size_t)p * 32 * K + k0, &AsH[p * 2048 + w * 512]);
            glds16(Al + aoff + (size_t)p * 32 * K + k0, &AsL[p * 2048 + w * 512]);
        }
        #pragma unroll
        for (int p = 0; p < 2; ++p) {
            glds16(Wh + boff + (size_t)p * 32 * K + k0, &BsH[p * 2048 + w * 512]);
            glds16(Wl + boff + (size_t)p * 32 * K + k0, &BsL[p * 2048 + w * 512]);
        }
        __syncthreads();
        #pragma unroll
        for (int ks = 0; ks < 2; ++ks) {
            short8 bh[2], bl[2];
            #pragma unroll
            for (int n = 0; n < 2; ++n) {
                int rB = wc * 32 + n * 16 + fr;
                int sl = ((ks * 4 + fg) ^ (rB & 7)) << 3;
                bh[n] = *(const short8*)&BsH[rB * 64 + sl];
                bl[n] = *(const short8*)&BsL[rB * 64 + sl];
            }
            #pragma unroll
            for (int m = 0; m < MREP; ++m) {
                int rA = wr * MREP * 16 + m * 16 + fr;
                int sl = ((ks * 4 + fg) ^ (rA & 7)) << 3;
                short8 ah = *(const short8*)&AsH[rA * 64 + sl];
                short8 al = *(const short8*)&AsL[rA * 64 + sl];
                #pragma unroll
                for (int n = 0; n < 2; ++n) {
                    acc[m][n] = __builtin_amdgcn_mfma_f32_16x16x32_bf16(ah, bh[n], acc[m][n], 0, 0, 0);
                    acc[m][n] = __builtin_amdgcn_mfma_f32_16x16x32_bf16(ah, bl[n], acc[m][n], 0, 0, 0);
                    acc[m][n] = __builtin_amdgcn_mfma_f32_16x16x32_bf16(al, bh[n], acc[m][n], 0, 0, 0);
                }
            }
        }
        __syncthreads();
    }

    #pragma unroll
    for (int n = 0; n < 2; ++n) {
        int col = col0 + wc * 32 + n * 16 + fr;
        float bv = bias[col];
        #pragma unroll
        for (int m = 0; m < MREP; ++m) {
            #pragma unroll
            for (int r = 0; r < 4; ++r) {
                int row = row0 + wr * MREP * 16 + m * 16 + fg * 4 + r;
                float v = acc[m][n][r] + bv;
                if (ACT) v = gelu_exact(v);
                size_t o = (size_t)row * N + col;
                if (OUT_SPLIT) {
                    ushort_t h = f2bf(v);
                    Oh[o] = h;
                    Ol[o] = f2bf(v - bf2f(h));
                } else {
                    outF[o] = v;
                }
            }
        }
    }
}

// ---------------- per-class RBF distance via bf16x3 MFMA ----------------
// v2: hi|lo interleaved 128B LDS rows (XOR-8, 2-way banks = free) +
//     full double-buffer with counted vmcnt (loads in flight across barriers).
// LDS (dynamic, 80KB): A[2][64][64] @0, B[2][256][64] @8192; red aliases A0.
__global__ __launch_bounds__(256)
void rbf_mfma_kernel(const ushort_t* __restrict__ zh,
                     const ushort_t* __restrict__ zl,
                     const ushort_t* __restrict__ cwh,
                     const ushort_t* __restrict__ cwl,
                     const float* __restrict__ cent,
                     float* __restrict__ logk) {
    extern __shared__ short smem[];   // 40960 shorts = 80KB
    const int tid  = threadIdx.x;
    const int lane = tid & 63;
    const int w    = tid >> 6;
    const int fr   = lane & 15;
    const int fg   = lane >> 4;

    const int bid = blockIdx.x;
    const int wg  = (bid & 7) * 400 + (bid >> 3);
    const int c    = wg >> 4;
    const int row0 = (wg & 15) * 64;

    // staging: lane -> (row = tid>>3, slot = tid&7); logical source slot
    // ss = slot ^ (row&7); ss<4 -> hi k-group ss, ss>=4 -> lo k-group ss-4.
    const int srow8 = tid >> 3;                    // 0..31
    const int ss    = (tid & 7) ^ (srow8 & 7);
    const int kofs  = (ss & 3) * 8;
    const ushort_t* zsel  = (ss < 4) ? zh  : zl;
    const ushort_t* cwsel = (ss < 4) ? cwh : cwl;
    const ushort_t* gA = zsel  + (size_t)(row0 + srow8) * E_ + kofs;
    const ushort_t* gB = cwsel + (size_t)c * 65536 + (size_t)srow8 * E_ + kofs;

    f32x4 acc[4][4];
    #pragma unroll
    for (int m = 0; m < 4; ++m)
        #pragma unroll
        for (int n = 0; n < 4; ++n)
            acc[m][n] = (f32x4){0.f, 0.f, 0.f, 0.f};

    // --- staging helpers (10 glds per tile: 2 A + 8 B) ---
    auto STAGE = [&](int t, int buf) {
        const int ke = t * 32;
        #pragma unroll
        for (int i = 0; i < 2; ++i)
            glds16(gA + (size_t)i * 32 * E_ + ke,
                   &smem[buf * 4096 + i * 2048 + w * 512]);
        #pragma unroll
        for (int i = 0; i < 8; ++i)
            glds16(gB + (size_t)i * 32 * E_ + ke,
                   &smem[8192 + buf * 16384 + i * 2048 + w * 512]);
    };

    auto COMPUTE = [&](int buf) {
        const short* Ab = &smem[buf * 4096];
        const short* Bb = &smem[8192 + buf * 16384];
        short8 bh[4], bl[4];
        #pragma unroll
        for (int n = 0; n < 4; ++n) {
            int d = w * 64 + n * 16 + fr;
            bh[n] = *(const short8*)&Bb[d * 64 + ((fg       ^ (d & 7)) << 3)];
            bl[n] = *(const short8*)&Bb[d * 64 + (((4 + fg) ^ (d & 7)) << 3)];
        }
        #pragma unroll
        for (int m = 0; m < 4; ++m) {
            int r = m * 16 + fr;
            short8 ah = *(const short8*)&Ab[r * 64 + ((fg       ^ (r & 7)) << 3)];
            short8 al = *(const short8*)&Ab[r * 64 + (((4 + fg) ^ (r & 7)) << 3)];
            #pragma unroll
            for (int n = 0; n < 4; ++n) {
                acc[m][n] = __builtin_amdgcn_mfma_f32_16x16x32_bf16(ah, bh[n], acc[m][n], 0, 0, 0);
                acc[m][n] = __builtin_amdgcn_mfma_f32_16x16x32_bf16(ah, bl[n], acc[m][n], 0, 0, 0);
                acc[m][n] = __builtin_amdgcn_mfma_f32_16x16x32_bf16(al, bh[n], acc[m][n], 0, 0, 0);
            }
        }
    };

    // --- pipelined K loop: 8 tiles of BK=32 ---
    STAGE(0, 0);                                    // 10 outstanding
    for (int t = 0; t < 7; ++t) {
        STAGE(t + 1, (t + 1) & 1);                  // +10 (20 outstanding)
        asm volatile("s_waitcnt vmcnt(10)" ::: "memory");  // tile t landed
        __builtin_amdgcn_s_barrier();
        __builtin_amdgcn_sched_barrier(0);
        COMPUTE(t & 1);
        __builtin_amdgcn_s_barrier();               // reads done before overwrite
    }
    asm volatile("s_waitcnt vmcnt(0)" ::: "memory");
    __builtin_amdgcn_s_barrier();
    __builtin_amdgcn_sched_barrier(0);
    COMPUTE(1);

    // --- epilogue: dist_sq per row (red aliases A0, dead since t=6) ---
    float cmu[4];
    #pragma unroll
    for (int n = 0; n < 4; ++n) cmu[n] = cent[(size_t)c * E_ + w * 64 + n * 16 + fr];

    __syncthreads();   // all waves done with LDS before aliasing red over A0
    float* red = (float*)smem;   // [64][4]
    #pragma unroll
    for (int m = 0; m < 4; ++m) {
        #pragma unroll
        for (int r = 0; r < 4; ++r) {
            float p = 0.f;
            #pragma unroll
            for (int n = 0; n < 4; ++n) {
                float d = acc[m][n][r] - cmu[n];
                p = fmaf(d, d, p);
            }
            p += __shfl_xor(p, 1, 64);
            p += __shfl_xor(p, 2, 64);
            p += __shfl_xor(p, 4, 64);
            p += __shfl_xor(p, 8, 64);
            if (fr == 0) red[(m * 16 + fg * 4 + r) * 4 + w] = p;
        }
    }
    __syncthreads();
    if (tid < 64) {
        float s = red[tid * 4 + 0] + red[tid * 4 + 1] + red[tid * 4 + 2] + red[tid * 4 + 3];
        logk[(size_t)(row0 + tid) * C_ + c] = NEG_INV_2LS2 * s;
    }
}

// ---------------- softmax + outputs ----------------
__global__ __launch_bounds__(64)
void out_kernel(const float* __restrict__ logk, float* __restrict__ dout) {
    const int b = blockIdx.x;
    const int t = threadIdx.x;
    const float* lr = logk + (size_t)b * C_;
    float v[4];
    float m = -INFINITY;
    #pragma unroll
    for (int i = 0; i < 4; ++i) {
        int idx = t + i * 64;
        v[i] = (idx < C_) ? lr[idx] : -INFINITY;
        m = fmaxf(m, v[i]);
    }
    #pragma unroll
    for (int off = 32; off > 0; off >>= 1) m = fmaxf(m, __shfl_xor(m, off, 64));
    float s = 0.f;
    #pragma unroll
    for (int i = 0; i < 4; ++i) {
        int idx = t + i * 64;
        if (idx < C_) s += expf(v[i] - m);
    }
    #pragma unroll
    for (int off = 32; off > 0; off >>= 1) s += __shfl_xor(s, off, 64);
    const float inv = 1.0f / s;
    #pragma unroll
    for (int i = 0; i < 4; ++i) {
        int idx = t + i * 64;
        if (idx < C_) {
            float p = expf(v[i] - m) * inv;
            dout[(size_t)b * C_ + idx] = p;
            dout[(size_t)204800 + (size_t)b * C_ + idx] = p;
            dout[(size_t)409600 + (size_t)b * C_ + idx] = expf(v[i]);
        }
    }
    if (t == 0) dout[(size_t)614400 + b] = 1.0f - expf(m);
}

// ---------------- launcher ----------------
extern "C" void kernel_launch(void* const* d_in, const int* in_sizes, int n_in,
                              void* d_out, int out_size, void* d_ws, size_t ws_size,
                              hipStream_t stream) {
    const float* features = (const float*)d_in[0];
    const float* ln1_g = (const float*)d_in[1];
    const float* ln1_b = (const float*)d_in[2];
    const float* W1    = (const float*)d_in[3];
    const float* b1    = (const float*)d_in[4];
    const float* ln2_g = (const float*)d_in[5];
    const float* ln2_b = (const float*)d_in[6];
    const float* W2    = (const float*)d_in[7];
    const float* b2    = (const float*)d_in[8];
    const float* W3    = (const float*)d_in[9];
    const float* b3    = (const float*)d_in[10];
    const float* cw    = (const float*)d_in[11];
    const float* cent  = (const float*)d_in[12];
    float* out = (float*)d_out;
    float* ws  = (float*)d_ws;

    // fp32 scratch
    float* h1 = ws;                       // [B, HIDDEN]
    float* lk = ws + 2097152;             // [B, C]
    // bf16 split scratch
    ushort_t* u = (ushort_t*)(ws + 2097152 + 204800);
    size_t o = 0;
    ushort_t* h0h = u + o; o += (size_t)B_ * EMBED_;
    ushort_t* h0l = u + o; o += (size_t)B_ * EMBED_;
    ushort_t* h1h = u + o; o += (size_t)B_ * HIDDEN_;
    ushort_t* h1l = u + o; o += (size_t)B_ * HIDDEN_;
    ushort_t* h2h = u + o; o += (size_t)B_ * HIDDEN_;
    ushort_t* h2l = u + o; o += (size_t)B_ * HIDDEN_;
    ushort_t* zh  = u + o; o += (size_t)B_ * E_;
    ushort_t* zl  = u + o; o += (size_t)B_ * E_;
    ushort_t* w1h = u + o; o += (size_t)EMBED_ * HIDDEN_;
    ushort_t* w1l = u + o; o += (size_t)EMBED_ * HIDDEN_;
    ushort_t* w2h = u + o; o += (size_t)HIDDEN_ * HIDDEN_;
    ushort_t* w2l = u + o; o += (size_t)HIDDEN_ * HIDDEN_;
    ushort_t* w3h = u + o; o += (size_t)HIDDEN_ * E_;
    ushort_t* w3l = u + o; o += (size_t)HIDDEN_ * E_;
    ushort_t* cwh = u + o; o += (size_t)C_ * E_ * E_;
    ushort_t* cwl = u + o; o += (size_t)C_ * E_ * E_;

    // weight conversions (input-only dependencies) first
    tconv_kernel<<<dim3(C_, 16), 256, 0, stream>>>(cw, cwh, cwl, E_, E_);
    tconv_kernel<<<dim3(1, (EMBED_ / 64) * (HIDDEN_ / 64)), 256, 0, stream>>>(W1, w1h, w1l, EMBED_, HIDDEN_);
    tconv_kernel<<<dim3(1, (HIDDEN_ / 64) * (HIDDEN_ / 64)), 256, 0, stream>>>(W2, w2h, w2l, HIDDEN_, HIDDEN_);
    tconv_kernel<<<dim3(1, (HIDDEN_ / 64) * (E_ / 64)), 256, 0, stream>>>(W3, w3h, w3l, HIDDEN_, E_);

    ln_split_kernel<EMBED_><<<B_, 256, 0, stream>>>(features, ln1_g, ln1_b, h0h, h0l);

    mfma_gemm_kernel<2, 1, 0><<<(HIDDEN_ / 64) * (B_ / 64), 256, 0, stream>>>(
        h0h, h0l, w1h, w1l, b1, h1, nullptr, nullptr, B_, HIDDEN_, EMBED_);

    ln_split_kernel<HIDDEN_><<<B_, 256, 0, stream>>>(h1, ln2_g, ln2_b, h1h, h1l);

    mfma_gemm_kernel<2, 1, 1><<<(HIDDEN_ / 64) * (B_ / 64), 256, 0, stream>>>(
        h1h, h1l, w2h, w2l, b2, nullptr, h2h, h2l, B_, HIDDEN_, HIDDEN_);

    mfma_gemm_kernel<1, 0, 1><<<(E_ / 64) * (B_ / 32), 256, 0, stream>>>(
        h2h, h2l, w3h, w3l, b3, nullptr, zh, zl, B_, E_, HIDDEN_);

    rbf_mfma_kernel<<<3200, 256, 81920, stream>>>(zh, zl, cwh, cwl, cent, lk);

    out_kernel<<<B_, 64, 0, stream>>>(lk, out);
}